// Round 1
// baseline (4166.672 us; speedup 1.0000x reference)
//
#include <hip/hip_runtime.h>

typedef __attribute__((ext_vector_type(4))) float f32x4;
typedef __attribute__((ext_vector_type(8))) short bf16x8;
typedef __attribute__((ext_vector_type(4))) int i32x4;
typedef unsigned short u16;
typedef __attribute__((ext_vector_type(4))) unsigned short u16x4;

#define EPS 1.1920929e-07f
#define S 1024
#define D 1024
#define P 64
#define NV 151936

__device__ __forceinline__ u16 f2bf(float f) {
  unsigned u = __float_as_uint(f);
  return (u16)((u + 0x7fffu + ((u >> 16) & 1u)) >> 16);
}

__device__ __forceinline__ float block_sum256(float v, float* sbuf) {
  #pragma unroll
  for (int off = 32; off; off >>= 1) v += __shfl_down(v, off);
  int lane = threadIdx.x & 63, w = threadIdx.x >> 6;
  if (lane == 0) sbuf[w] = v;
  __syncthreads();
  return sbuf[0] + sbuf[1] + sbuf[2] + sbuf[3];
}

// ---------------- embedding gather ----------------
__global__ void k_gather(const int* __restrict__ tokens, const float* __restrict__ table,
                         float* __restrict__ x) {
  int s = blockIdx.x;
  int t = tokens[s];
  const f32x4* src = (const f32x4*)(table + (size_t)t * D);
  f32x4* dst = (f32x4*)(x + (size_t)s * D);
  dst[threadIdx.x] = src[threadIdx.x];
}

// ---------------- column partial sums (for x.mean over S) ----------------
__global__ void k_colpart(const float* __restrict__ x, float* __restrict__ cp) {
  int b = blockIdx.x, t = threadIdx.x;
  f32x4 acc = 0.f;
  for (int r = 0; r < 32; ++r) {
    f32x4 v = *(const f32x4*)(x + (size_t)(b * 32 + r) * D + t * 4);
    acc += v;
  }
  *(f32x4*)(cp + b * D + t * 4) = acc;
}

// ---------------- angles -> cos/sin table ----------------
__global__ void k_angles(const float* __restrict__ cp, const float* __restrict__ agw,
                         const float* __restrict__ bang, float* __restrict__ trig) {
  int p = blockIdx.x, l = threadIdx.x;  // 64 blocks x 64 threads
  float sum = 0.f;
  for (int d = l; d < D; d += 64) {
    float xm = 0.f;
    #pragma unroll 8
    for (int b = 0; b < 32; ++b) xm += cp[b * D + d];
    sum += xm * agw[p * D + d];
  }
  #pragma unroll
  for (int off = 32; off; off >>= 1) sum += __shfl_down(sum, off);
  if (l == 0) {
    float ang = bang[p] + 0.1f * (sum * (1.f / (float)S));
    trig[p] = cosf(ang);
    trig[64 + p] = sinf(ang);
  }
}

// ---------------- causal EMA via windowed conv (exact to f32: dec^96 ~ 6e-15) --------
#define TAPS 96
#define CSR 64
#define CDC 64
__global__ __launch_bounds__(256) void k_causal(const float* __restrict__ x,
                                                float* __restrict__ causal,
                                                const float* __restrict__ decay_p) {
  __shared__ float tile[CSR + TAPS - 1][CDC];  // 159*64*4 = 40.7KB
  int s0 = blockIdx.x * CSR;
  int d0 = blockIdx.y * CDC;
  float dp = decay_p[0];
  float dec = 1.f / (1.f + expf(-dp));
  for (int idx = threadIdx.x; idx < (CSR + TAPS - 1) * CDC; idx += 256) {
    int r = idx / CDC, c = idx % CDC;
    int gs = s0 - (TAPS - 1) + r;
    tile[r][c] = (gs >= 0) ? x[(size_t)gs * D + d0 + c] : 0.f;
  }
  __syncthreads();
  int c = threadIdx.x % CDC;
  int r0 = threadIdx.x / CDC;
  for (int rr = r0; rr < CSR; rr += 4) {
    float acc = 0.f;
    float w = 1.f - dec;
    int base = rr + TAPS - 1;
    #pragma unroll 8
    for (int j = 0; j < TAPS; ++j) {
      acc += w * tile[base - j][c];
      w *= dec;
    }
    causal[(size_t)(s0 + rr) * D + d0 + c] = acc;
  }
}

// ---------------- generic f32 GEMM: C[m,n] = (ADD? C : 0) + sum_k A[m,k]*B[n,k] -----
template <bool ADD>
__global__ __launch_bounds__(256) void k_gemm_f32(const float* __restrict__ A,
                                                  const float* __restrict__ B,
                                                  float* __restrict__ C, int M, int N, int K) {
  __shared__ float As[32][68];  // transposed [kk][r], 16B-aligned rows
  __shared__ float Bs[32][68];
  int m0 = blockIdx.x * 64, n0 = blockIdx.y * 64;
  int t = threadIdx.x;
  int tx = t % 16, ty = t / 16;
  f32x4 accv[4];
  #pragma unroll
  for (int i = 0; i < 4; ++i) accv[i] = 0.f;
  float acc[4][4] = {};
  for (int k0 = 0; k0 < K; k0 += 32) {
    #pragma unroll
    for (int it = 0; it < 2; ++it) {
      int c = t + it * 256;          // 0..511
      int r = c >> 3;                 // 0..63
      int kc = (c & 7) << 2;          // 0..28 step 4
      f32x4 va = *(const f32x4*)(A + (size_t)(m0 + r) * K + k0 + kc);
      f32x4 vb = *(const f32x4*)(B + (size_t)(n0 + r) * K + k0 + kc);
      #pragma unroll
      for (int q = 0; q < 4; ++q) { As[kc + q][r] = va[q]; Bs[kc + q][r] = vb[q]; }
    }
    __syncthreads();
    #pragma unroll
    for (int kk = 0; kk < 32; ++kk) {
      f32x4 av = *(const f32x4*)&As[kk][ty * 4];
      f32x4 bv = *(const f32x4*)&Bs[kk][tx * 4];
      #pragma unroll
      for (int i = 0; i < 4; ++i)
        #pragma unroll
        for (int j = 0; j < 4; ++j) acc[i][j] += av[i] * bv[j];
    }
    __syncthreads();
  }
  #pragma unroll
  for (int i = 0; i < 4; ++i)
    #pragma unroll
    for (int j = 0; j < 4; ++j) {
      size_t idx = (size_t)(m0 + ty * 4 + i) * N + n0 + tx * 4 + j;
      C[idx] = ADD ? (C[idx] + acc[i][j]) : acc[i][j];
    }
}

// ---------------- rotation ----------------
__global__ void k_rot(const float* __restrict__ proj, const float* __restrict__ trig,
                      float* __restrict__ rot) {
  int idx = blockIdx.x * 256 + threadIdx.x;  // 1024*64
  int s = idx >> 6, p = idx & 63;
  float a = proj[s * 128 + p];
  float b = proj[s * 128 + 64 + p];
  float ca = trig[p], sa = trig[64 + p];
  rot[s * 128 + p] = a * ca - b * sa;
  rot[s * 128 + 64 + p] = a * sa + b * ca;
}

// ---------------- fused: x_rot=x+R; act=silu(x_rot*sc+sh); x+=rmsnorm(act-x)*nw ----
__global__ __launch_bounds__(256) void k_epilogue(float* __restrict__ x, const float* __restrict__ R,
                                                  const float* __restrict__ scale,
                                                  const float* __restrict__ shift,
                                                  const float* __restrict__ nw) {
  __shared__ float sbuf[4];
  int s = blockIdx.x, t = threadIdx.x;
  f32x4 xv = *(const f32x4*)(x + (size_t)s * D + t * 4);
  f32x4 rv = *(const f32x4*)(R + (size_t)s * D + t * 4);
  f32x4 sc = *(const f32x4*)(scale + t * 4);
  f32x4 sh = *(const f32x4*)(shift + t * 4);
  float y[4];
  float ss = 0.f;
  #pragma unroll
  for (int c = 0; c < 4; ++c) {
    float xr = xv[c] + rv[c];
    float tt = xr * sc[c] + sh[c];
    float act = tt / (1.f + expf(-tt));
    y[c] = act - xv[c];
    ss += y[c] * y[c];
  }
  float total = block_sum256(ss, sbuf);
  float inv = rsqrtf(total * (1.f / (float)D) + EPS);
  f32x4 nwv = *(const f32x4*)(nw + t * 4);
  f32x4 o;
  #pragma unroll
  for (int c = 0; c < 4; ++c) o[c] = xv[c] + y[c] * inv * nwv[c];
  *(f32x4*)(x + (size_t)s * D + t * 4) = o;
}

// ---------------- final rmsnorm -> bf16 ----------------
__global__ __launch_bounds__(256) void k_outnorm(const float* __restrict__ x,
                                                 const float* __restrict__ w,
                                                 u16* __restrict__ xn) {
  __shared__ float sbuf[4];
  int s = blockIdx.x, t = threadIdx.x;
  f32x4 xv = *(const f32x4*)(x + (size_t)s * D + t * 4);
  float ss = xv[0] * xv[0] + xv[1] * xv[1] + xv[2] * xv[2] + xv[3] * xv[3];
  float total = block_sum256(ss, sbuf);
  float inv = rsqrtf(total * (1.f / (float)D) + EPS);
  f32x4 wv = *(const f32x4*)(w + t * 4);
  u16x4 o;
  #pragma unroll
  for (int c = 0; c < 4; ++c) o[c] = f2bf(xv[c] * inv * wv[c]);
  *(u16x4*)(xn + (size_t)s * D + t * 4) = o;
}

// ---------------- lm_head GEMM: out[m,v] = sum_d A[m,d]*W[v,d], bf16 MFMA ----------
__global__ __launch_bounds__(256) void k_lm(const u16* __restrict__ A, const float* __restrict__ W,
                                            float* __restrict__ out) {
  __shared__ u16 As[128][40];  // row = 80B, 16B aligned
  __shared__ u16 Bs[128][40];
  const int m0 = blockIdx.x * 128;
  const int n0 = blockIdx.y * 128;
  const int t = threadIdx.x;
  const int wave = t >> 6, lane = t & 63;
  const int wm = (wave >> 1) * 64, wn = (wave & 1) * 64;
  const int fr = lane & 15, kb = lane >> 4;
  f32x4 acc[4][4];
  #pragma unroll
  for (int i = 0; i < 4; ++i)
    #pragma unroll
    for (int j = 0; j < 4; ++j) acc[i][j] = 0.f;

  for (int k0 = 0; k0 < D; k0 += 32) {
    // stage A (bf16): 128 rows x 32 k = 512 x 16B
    #pragma unroll
    for (int it = 0; it < 2; ++it) {
      int c = t + it * 256;
      int r = c >> 2, kc = (c & 3) << 3;
      *(i32x4*)&As[r][kc] = *(const i32x4*)(A + (size_t)(m0 + r) * D + k0 + kc);
    }
    // stage B (f32 -> bf16): 128 rows x 32 k = 1024 x float4
    #pragma unroll
    for (int it = 0; it < 4; ++it) {
      int c = t + it * 256;
      int r = c >> 3, kc = (c & 7) << 2;
      f32x4 v = *(const f32x4*)(W + (size_t)(n0 + r) * D + k0 + kc);
      u16x4 pk;
      #pragma unroll
      for (int e = 0; e < 4; ++e) pk[e] = f2bf(v[e]);
      *(u16x4*)&Bs[r][kc] = pk;
    }
    __syncthreads();
    bf16x8 a[4], b[4];
    #pragma unroll
    for (int i = 0; i < 4; ++i) a[i] = *(const bf16x8*)&As[wm + i * 16 + fr][kb * 8];
    #pragma unroll
    for (int j = 0; j < 4; ++j) b[j] = *(const bf16x8*)&Bs[wn + j * 16 + fr][kb * 8];
    #pragma unroll
    for (int i = 0; i < 4; ++i)
      #pragma unroll
      for (int j = 0; j < 4; ++j)
        acc[i][j] = __builtin_amdgcn_mfma_f32_16x16x32_bf16(a[i], b[j], acc[i][j], 0, 0, 0);
    __syncthreads();
  }
  #pragma unroll
  for (int i = 0; i < 4; ++i)
    #pragma unroll
    for (int j = 0; j < 4; ++j)
      #pragma unroll
      for (int rg = 0; rg < 4; ++rg) {
        int m = m0 + wm + i * 16 + kb * 4 + rg;
        int n = n0 + wn + j * 16 + fr;
        out[(size_t)m * NV + n] = acc[i][j][rg];
      }
}

extern "C" void kernel_launch(void* const* d_in, const int* in_sizes, int n_in,
                              void* d_out, int out_size, void* d_ws, size_t ws_size,
                              hipStream_t stream) {
  const int* tokens = (const int*)d_in[0];
  const float* embed = (const float*)d_in[1];
  const float* Wp = (const float*)d_in[2];
  const float* Wb = (const float*)d_in[3];
  const float* bang = (const float*)d_in[4];
  const float* agw = (const float*)d_in[5];
  const float* scales = (const float*)d_in[6];
  const float* shifts = (const float*)d_in[7];
  const float* normw = (const float*)d_in[8];
  const float* decay = (const float*)d_in[9];
  const float* gatew = (const float*)d_in[10];
  const float* onorm = (const float*)d_in[11];
  const float* lmw = (const float*)d_in[12];
  float* out = (float*)d_out;

  char* ws = (char*)d_ws;
  float* x = (float*)ws;                              // 4MB
  float* R = (float*)(ws + (4u << 20));               // 4MB (causal / back-proj result)
  float* proj = (float*)(ws + (8u << 20));            // 512KB
  float* rot = (float*)(ws + (8u << 20) + (512u << 10));  // 512KB
  float* colpart = (float*)(ws + (9u << 20));         // 128KB
  float* trig = (float*)(ws + (9u << 20) + (256u << 10)); // 512B
  u16* xn = (u16*)(ws + (10u << 20));                 // 2MB

  k_gather<<<S, 256, 0, stream>>>(tokens, embed, x);

  for (int i = 0; i < 28; ++i) {
    k_colpart<<<32, 256, 0, stream>>>(x, colpart);
    if ((i & 3) == 0) {
      k_causal<<<dim3(S / CSR, D / CDC), 256, 0, stream>>>(x, R, decay);
      k_gemm_f32<true><<<dim3(16, 16), 256, 0, stream>>>(R, gatew, x, S, D, D);
    }
    k_angles<<<64, 64, 0, stream>>>(colpart, agw, bang + i * P, trig);
    k_gemm_f32<false><<<dim3(16, 2), 256, 0, stream>>>(x, Wp + (size_t)i * 128 * D, proj, S, 128, D);
    k_rot<<<256, 256, 0, stream>>>(proj, trig, rot);
    k_gemm_f32<false><<<dim3(16, 16), 256, 0, stream>>>(rot, Wb + (size_t)i * D * 128, R, S, D, 128);
    k_epilogue<<<S, 256, 0, stream>>>(x, R, scales + i * D, shifts + i * D, normw + i * D);
  }

  k_outnorm<<<S, 256, 0, stream>>>(x, onorm, xn);
  k_lm<<<dim3(8, NV / 128), 256, 0, stream>>>(xn, lmw, out);
}

// Round 4
// 3671.063 us; speedup vs baseline: 1.1350x; 1.1350x over previous
//
#include <hip/hip_runtime.h>

typedef __attribute__((ext_vector_type(4))) float f32x4;
typedef __attribute__((ext_vector_type(8))) short bf16x8;
typedef unsigned short u16;
typedef unsigned int u32;
typedef __attribute__((ext_vector_type(4))) unsigned short u16x4;

#define EPS 1.1920929e-07f
#define S 1024
#define D 1024
#define NV 151936
#define NCYC 28

__device__ __forceinline__ u16 f2bf(float f) {  // RNE
  u32 u = __float_as_uint(f);
  return (u16)((u + 0x7fffu + ((u >> 16) & 1u)) >> 16);
}
__device__ __forceinline__ float bf2f(u16 h) {
  return __uint_as_float((u32)h << 16);
}
struct bfpair { u16 h, l; };
__device__ __forceinline__ bfpair split_bf(float v) {
  bfpair r;
  r.h = f2bf(v);
  r.l = f2bf(v - bf2f(r.h));
  return r;
}

__device__ __forceinline__ void gl16(const void* g, void* s) {
  __builtin_amdgcn_global_load_lds((const __attribute__((address_space(1))) u32*)g,
                                   (__attribute__((address_space(3))) u32*)s, 16, 0, 0);
}

__device__ __forceinline__ float block_sum256(float v, float* sbuf) {
  #pragma unroll
  for (int off = 32; off; off >>= 1) v += __shfl_down(v, off);
  int lane = threadIdx.x & 63, w = threadIdx.x >> 6;
  if (lane == 0) sbuf[w] = v;
  __syncthreads();
  return sbuf[0] + sbuf[1] + sbuf[2] + sbuf[3];
}

// ---------------- f32 -> bf16 (RNE) ----------------
__global__ void k_cvt(const float* __restrict__ src, u16* __restrict__ dst, size_t n4) {
  size_t i = (size_t)blockIdx.x * 256 + threadIdx.x;
  size_t stride = (size_t)gridDim.x * 256;
  for (; i < n4; i += stride) {
    f32x4 v = ((const f32x4*)src)[i];
    u16x4 o;
    #pragma unroll
    for (int e = 0; e < 4; ++e) o[e] = f2bf(v[e]);
    ((u16x4*)dst)[i] = o;
  }
}

// ---------------- f32 -> (hi, lo) bf16 split ----------------
__global__ void k_cvt2(const float* __restrict__ src, u16* __restrict__ dh,
                       u16* __restrict__ dl, size_t n4) {
  size_t i = (size_t)blockIdx.x * 256 + threadIdx.x;
  size_t stride = (size_t)gridDim.x * 256;
  for (; i < n4; i += stride) {
    f32x4 v = ((const f32x4*)src)[i];
    u16x4 oh, ol;
    #pragma unroll
    for (int e = 0; e < 4; ++e) { bfpair p = split_bf(v[e]); oh[e] = p.h; ol[e] = p.l; }
    ((u16x4*)dh)[i] = oh;
    ((u16x4*)dl)[i] = ol;
  }
}

// ---------------- embedding gather (f32 + split mirror) ----------------
__global__ void k_gather(const int* __restrict__ tokens, const float* __restrict__ table,
                         float* __restrict__ x, u16* __restrict__ xh, u16* __restrict__ xl) {
  int s = blockIdx.x, t = threadIdx.x;
  int tok = tokens[s];
  f32x4 v = ((const f32x4*)(table + (size_t)tok * D))[t];
  ((f32x4*)(x + (size_t)s * D))[t] = v;
  u16x4 oh, ol;
  #pragma unroll
  for (int e = 0; e < 4; ++e) { bfpair p = split_bf(v[e]); oh[e] = p.h; ol[e] = p.l; }
  ((u16x4*)(xh + (size_t)s * D))[t] = oh;
  ((u16x4*)(xl + (size_t)s * D))[t] = ol;
}

// ---------------- column partial sums ----------------
__global__ void k_colpart(const float* __restrict__ x, float* __restrict__ cp) {
  int b = blockIdx.x, t = threadIdx.x;
  f32x4 acc = 0.f;
  for (int r = 0; r < 32; ++r)
    acc += *(const f32x4*)(x + (size_t)(b * 32 + r) * D + t * 4);
  *(f32x4*)(cp + b * D + t * 4) = acc;
}

// ---------------- angles -> cos/sin table ----------------
__global__ void k_angles(const float* __restrict__ cp, const float* __restrict__ agw,
                         const float* __restrict__ bang, float* __restrict__ trig) {
  int p = blockIdx.x, l = threadIdx.x;
  float sum = 0.f;
  for (int d = l; d < D; d += 64) {
    float xm = 0.f;
    #pragma unroll 8
    for (int b = 0; b < 32; ++b) xm += cp[b * D + d];
    sum += xm * agw[p * D + d];
  }
  #pragma unroll
  for (int off = 32; off; off >>= 1) sum += __shfl_down(sum, off);
  if (l == 0) {
    float ang = bang[p] + 0.1f * (sum * (1.f / (float)S));
    trig[p] = cosf(ang);
    trig[64 + p] = sinf(ang);
  }
}

// ---------------- causal EMA via windowed conv (dec^95 ~ 8e-15) -> split -----------
#define TAPS 96
#define CSR 64
#define CDC 64
__global__ __launch_bounds__(256) void k_causal(const float* __restrict__ x,
                                                u16* __restrict__ Rh, u16* __restrict__ Rl,
                                                const float* __restrict__ decay_p) {
  __shared__ float tile[CSR + TAPS - 1][CDC];
  int s0 = blockIdx.x * CSR, d0 = blockIdx.y * CDC;
  float dec = 1.f / (1.f + expf(-decay_p[0]));
  for (int idx = threadIdx.x; idx < (CSR + TAPS - 1) * CDC; idx += 256) {
    int r = idx / CDC, c = idx % CDC;
    int gs = s0 - (TAPS - 1) + r;
    tile[r][c] = (gs >= 0) ? x[(size_t)gs * D + d0 + c] : 0.f;
  }
  __syncthreads();
  int c = threadIdx.x % CDC, r0 = threadIdx.x / CDC;
  for (int rr = r0; rr < CSR; rr += 4) {
    float acc = 0.f, w = 1.f - dec;
    int base = rr + TAPS - 1;
    #pragma unroll 8
    for (int j = 0; j < TAPS; ++j) { acc += w * tile[base - j][c]; w *= dec; }
    bfpair p = split_bf(acc);
    Rh[(size_t)(s0 + rr) * D + d0 + c] = p.h;
    Rl[(size_t)(s0 + rr) * D + d0 + c] = p.l;
  }
}

// ------- split-bf16 MFMA GEMM (~f32 accurate): C[m,n] (+)= A[m,:]·B[n,:] -----------
// acc = Ah*Bh + Ah*Bl + Al*Bh  (AlBl dropped, ~2^-18 rel)
template <bool ADD, bool XBOUT>
__global__ __launch_bounds__(256) void k_gemm_s(const u16* __restrict__ Ah_,
                                                const u16* __restrict__ Al_,
                                                const u16* __restrict__ Bh_,
                                                const u16* __restrict__ Bl_,
                                                float* __restrict__ C,
                                                u16* __restrict__ Ch, u16* __restrict__ Cl,
                                                int N, int K) {
  __shared__ u16 Ash[128 * 64], Asl[128 * 64], Bsh[128 * 64], Bsl[128 * 64];
  const int m0 = blockIdx.x * 128, n0 = blockIdx.y * 128;
  const int t = threadIdx.x;
  const int wave = t >> 6, lane = t & 63;
  const int wm = (wave >> 1) * 64, wn = (wave & 1) * 64;
  const int fr = lane & 15, kb = lane >> 4;
  const int sr = t >> 3, skc = (t & 7) << 3;
  f32x4 acc[4][4];
  #pragma unroll
  for (int i = 0; i < 4; ++i)
    #pragma unroll
    for (int j = 0; j < 4; ++j) acc[i][j] = 0.f;

  for (int k0 = 0; k0 < K; k0 += 64) {
    #pragma unroll
    for (int it = 0; it < 4; ++it) {
      int r = it * 32 + sr;
      size_t ga = (size_t)(m0 + r) * K + k0 + skc;
      size_t gb = (size_t)(n0 + r) * K + k0 + skc;
      int so = r * 64 + skc;
      gl16(Ah_ + ga, Ash + so);
      gl16(Al_ + ga, Asl + so);
      gl16(Bh_ + gb, Bsh + so);
      gl16(Bl_ + gb, Bsl + so);
    }
    __syncthreads();
    #pragma unroll
    for (int ks = 0; ks < 2; ++ks) {
      bf16x8 ah[4], al[4], bh[4], bl[4];
      #pragma unroll
      for (int i = 0; i < 4; ++i) {
        int o = (wm + i * 16 + fr) * 64 + ks * 32 + kb * 8;
        ah[i] = *(const bf16x8*)&Ash[o];
        al[i] = *(const bf16x8*)&Asl[o];
      }
      #pragma unroll
      for (int j = 0; j < 4; ++j) {
        int o = (wn + j * 16 + fr) * 64 + ks * 32 + kb * 8;
        bh[j] = *(const bf16x8*)&Bsh[o];
        bl[j] = *(const bf16x8*)&Bsl[o];
      }
      #pragma unroll
      for (int i = 0; i < 4; ++i)
        #pragma unroll
        for (int j = 0; j < 4; ++j) {
          acc[i][j] = __builtin_amdgcn_mfma_f32_16x16x32_bf16(ah[i], bh[j], acc[i][j], 0, 0, 0);
          acc[i][j] = __builtin_amdgcn_mfma_f32_16x16x32_bf16(ah[i], bl[j], acc[i][j], 0, 0, 0);
          acc[i][j] = __builtin_amdgcn_mfma_f32_16x16x32_bf16(al[i], bh[j], acc[i][j], 0, 0, 0);
        }
    }
    __syncthreads();
  }
  #pragma unroll
  for (int i = 0; i < 4; ++i)
    #pragma unroll
    for (int j = 0; j < 4; ++j)
      #pragma unroll
      for (int rg = 0; rg < 4; ++rg) {
        int m = m0 + wm + i * 16 + kb * 4 + rg;
        int n = n0 + wn + j * 16 + fr;
        float v = acc[i][j][rg];
        if (ADD) v += C[(size_t)m * N + n];
        C[(size_t)m * N + n] = v;
        if (XBOUT) {
          bfpair p = split_bf(v);
          Ch[(size_t)m * N + n] = p.h;
          Cl[(size_t)m * N + n] = p.l;
        }
      }
}

// ---------------- proj GEMM (split) + fused rotation -> split rot ------------------
__global__ __launch_bounds__(256) void k_proj_rot(const u16* __restrict__ xh,
                                                  const u16* __restrict__ xl,
                                                  const u16* __restrict__ Bh_,
                                                  const u16* __restrict__ Bl_,
                                                  const float* __restrict__ trig,
                                                  u16* __restrict__ roth,
                                                  u16* __restrict__ rotl) {
  __shared__ u16 Ash[64 * 64], Asl[64 * 64], Bsh[128 * 64], Bsl[128 * 64];
  const int m0 = blockIdx.x * 64;
  const int t = threadIdx.x;
  const int wave = t >> 6, lane = t & 63;
  const int fr = lane & 15, kb = lane >> 4;
  const int sr = t >> 3, skc = (t & 7) << 3;
  f32x4 acc[8];
  #pragma unroll
  for (int j = 0; j < 8; ++j) acc[j] = 0.f;

  for (int k0 = 0; k0 < D; k0 += 64) {
    #pragma unroll
    for (int it = 0; it < 2; ++it) {
      int r = it * 32 + sr;
      size_t ga = (size_t)(m0 + r) * D + k0 + skc;
      gl16(xh + ga, Ash + r * 64 + skc);
      gl16(xl + ga, Asl + r * 64 + skc);
    }
    #pragma unroll
    for (int it = 0; it < 4; ++it) {
      int r = it * 32 + sr;
      size_t gb = (size_t)r * D + k0 + skc;
      gl16(Bh_ + gb, Bsh + r * 64 + skc);
      gl16(Bl_ + gb, Bsl + r * 64 + skc);
    }
    __syncthreads();
    #pragma unroll
    for (int ks = 0; ks < 2; ++ks) {
      int oa = (wave * 16 + fr) * 64 + ks * 32 + kb * 8;
      bf16x8 ah = *(const bf16x8*)&Ash[oa];
      bf16x8 al = *(const bf16x8*)&Asl[oa];
      #pragma unroll
      for (int j = 0; j < 8; ++j) {
        int ob = (j * 16 + fr) * 64 + ks * 32 + kb * 8;
        bf16x8 bh = *(const bf16x8*)&Bsh[ob];
        bf16x8 bl = *(const bf16x8*)&Bsl[ob];
        acc[j] = __builtin_amdgcn_mfma_f32_16x16x32_bf16(ah, bh, acc[j], 0, 0, 0);
        acc[j] = __builtin_amdgcn_mfma_f32_16x16x32_bf16(ah, bl, acc[j], 0, 0, 0);
        acc[j] = __builtin_amdgcn_mfma_f32_16x16x32_bf16(al, bh, acc[j], 0, 0, 0);
      }
    }
    __syncthreads();
  }
  #pragma unroll
  for (int j = 0; j < 4; ++j) {
    int p = j * 16 + fr;
    float ca = trig[p], sa = trig[64 + p];
    #pragma unroll
    for (int rg = 0; rg < 4; ++rg) {
      int m = m0 + wave * 16 + kb * 4 + rg;
      float va = acc[j][rg], vb = acc[j + 4][rg];
      float ra = va * ca - vb * sa;
      float rb = va * sa + vb * ca;
      bfpair pa = split_bf(ra);
      roth[m * 128 + p] = pa.h;
      rotl[m * 128 + p] = pa.l;
      bfpair pb = split_bf(rb);
      roth[m * 128 + 64 + p] = pb.h;
      rotl[m * 128 + 64 + p] = pb.l;
    }
  }
}

// ---------------- fused epilogue: x += rmsnorm(silu((x+R)*sc+sh) - x) * nw ---------
__global__ __launch_bounds__(256) void k_epilogue(float* __restrict__ x, u16* __restrict__ xh,
                                                  u16* __restrict__ xl,
                                                  const float* __restrict__ R,
                                                  const float* __restrict__ scale,
                                                  const float* __restrict__ shift,
                                                  const float* __restrict__ nw) {
  __shared__ float sbuf[4];
  int s = blockIdx.x, t = threadIdx.x;
  f32x4 xv = *(const f32x4*)(x + (size_t)s * D + t * 4);
  f32x4 rv = *(const f32x4*)(R + (size_t)s * D + t * 4);
  f32x4 sc = *(const f32x4*)(scale + t * 4);
  f32x4 sh = *(const f32x4*)(shift + t * 4);
  float y[4], ss = 0.f;
  #pragma unroll
  for (int c = 0; c < 4; ++c) {
    float xr = xv[c] + rv[c];
    float tt = xr * sc[c] + sh[c];
    float act = tt / (1.f + expf(-tt));
    y[c] = act - xv[c];
    ss += y[c] * y[c];
  }
  float total = block_sum256(ss, sbuf);
  float inv = rsqrtf(total * (1.f / (float)D) + EPS);
  f32x4 nwv = *(const f32x4*)(nw + t * 4);
  f32x4 o;
  u16x4 oh, ol;
  #pragma unroll
  for (int c = 0; c < 4; ++c) {
    o[c] = xv[c] + y[c] * inv * nwv[c];
    bfpair p = split_bf(o[c]);
    oh[c] = p.h;
    ol[c] = p.l;
  }
  *(f32x4*)(x + (size_t)s * D + t * 4) = o;
  *(u16x4*)(xh + (size_t)s * D + t * 4) = oh;
  *(u16x4*)(xl + (size_t)s * D + t * 4) = ol;
}

// ---------------- final rmsnorm -> bf16 ----------------
__global__ __launch_bounds__(256) void k_outnorm(const float* __restrict__ x,
                                                 const float* __restrict__ w,
                                                 u16* __restrict__ xn) {
  __shared__ float sbuf[4];
  int s = blockIdx.x, t = threadIdx.x;
  f32x4 xv = *(const f32x4*)(x + (size_t)s * D + t * 4);
  float total = block_sum256(xv[0]*xv[0] + xv[1]*xv[1] + xv[2]*xv[2] + xv[3]*xv[3], sbuf);
  float inv = rsqrtf(total * (1.f / (float)D) + EPS);
  f32x4 wv = *(const f32x4*)(w + t * 4);
  u16x4 o;
  #pragma unroll
  for (int c = 0; c < 4; ++c) o[c] = f2bf(xv[c] * inv * wv[c]);
  *(u16x4*)(xn + (size_t)s * D + t * 4) = o;
}

// ---------------- lm_head GEMM, m97-style, XCD-chunk swizzle -----------------------
// grid: 9496 = 8 m-tiles x 1187 n-tiles (1-D).
template <bool PRECONV>
__global__ __launch_bounds__(256) void k_lm(const u16* __restrict__ A,
                                            const void* __restrict__ Wsrc,
                                            float* __restrict__ out) {
  __shared__ u16 As[128 * 64];
  __shared__ u16 Bs[128 * 64];
  const int bid = blockIdx.x;
  const int lid = (bid & 7) * 1187 + (bid >> 3);  // bijective: 9496 = 8*1187
  const int m0 = (lid & 7) * 128;
  const int n0 = (lid >> 3) * 128;
  const int t = threadIdx.x;
  const int wave = t >> 6, lane = t & 63;
  const int wm = (wave >> 1) * 64, wn = (wave & 1) * 64;
  const int fr = lane & 15, kb = lane >> 4;
  const int sr = t >> 3, skc = (t & 7) << 3;
  const u16* Wb16 = (const u16*)Wsrc;
  const float* Wf = (const float*)Wsrc;
  f32x4 acc[4][4];
  #pragma unroll
  for (int i = 0; i < 4; ++i)
    #pragma unroll
    for (int j = 0; j < 4; ++j) acc[i][j] = 0.f;

  for (int k0 = 0; k0 < D; k0 += 64) {
    #pragma unroll
    for (int it = 0; it < 4; ++it) {
      int r = it * 32 + sr;
      gl16(A + (size_t)(m0 + r) * D + k0 + skc, As + r * 64 + skc);
    }
    if (PRECONV) {
      #pragma unroll
      for (int it = 0; it < 4; ++it) {
        int r = it * 32 + sr;
        gl16(Wb16 + (size_t)(n0 + r) * D + k0 + skc, Bs + r * 64 + skc);
      }
    } else {
      #pragma unroll
      for (int it = 0; it < 4; ++it) {
        int r = it * 32 + sr;
        const float* src = Wf + (size_t)(n0 + r) * D + k0 + skc;
        f32x4 v0 = *(const f32x4*)src;
        f32x4 v1 = *(const f32x4*)(src + 4);
        u16 h[8];
        #pragma unroll
        for (int e = 0; e < 4; ++e) { h[e] = f2bf(v0[e]); h[e + 4] = f2bf(v1[e]); }
        *(bf16x8*)&Bs[r * 64 + skc] = *(bf16x8*)h;
      }
    }
    __syncthreads();
    #pragma unroll
    for (int ks = 0; ks < 2; ++ks) {
      bf16x8 a[4], b[4];
      #pragma unroll
      for (int i = 0; i < 4; ++i) a[i] = *(const bf16x8*)&As[(wm + i * 16 + fr) * 64 + ks * 32 + kb * 8];
      #pragma unroll
      for (int j = 0; j < 4; ++j) b[j] = *(const bf16x8*)&Bs[(wn + j * 16 + fr) * 64 + ks * 32 + kb * 8];
      #pragma unroll
      for (int i = 0; i < 4; ++i)
        #pragma unroll
        for (int j = 0; j < 4; ++j)
          acc[i][j] = __builtin_amdgcn_mfma_f32_16x16x32_bf16(a[i], b[j], acc[i][j], 0, 0, 0);
    }
    __syncthreads();
  }
  #pragma unroll
  for (int i = 0; i < 4; ++i)
    #pragma unroll
    for (int j = 0; j < 4; ++j)
      #pragma unroll
      for (int rg = 0; rg < 4; ++rg) {
        int m = m0 + wm + i * 16 + kb * 4 + rg;
        int n = n0 + wn + j * 16 + fr;
        out[(size_t)m * NV + n] = acc[i][j][rg];
      }
}

extern "C" void kernel_launch(void* const* d_in, const int* in_sizes, int n_in,
                              void* d_out, int out_size, void* d_ws, size_t ws_size,
                              hipStream_t stream) {
  const int* tokens = (const int*)d_in[0];
  const float* embed = (const float*)d_in[1];
  const float* Wp = (const float*)d_in[2];
  const float* Wb = (const float*)d_in[3];
  const float* bang = (const float*)d_in[4];
  const float* agw = (const float*)d_in[5];
  const float* scales = (const float*)d_in[6];
  const float* shifts = (const float*)d_in[7];
  const float* normw = (const float*)d_in[8];
  const float* decay = (const float*)d_in[9];
  const float* gatew = (const float*)d_in[10];
  const float* onorm = (const float*)d_in[11];
  const float* lmw = (const float*)d_in[12];
  float* out = (float*)d_out;

  char* ws = (char*)d_ws;
  const size_t MB = 1u << 20;
  float* x = (float*)ws;                         // 4 MB
  u16* xh = (u16*)(ws + 4 * MB);                 // 2 MB
  u16* xl = (u16*)(ws + 6 * MB);                 // 2 MB
  float* R = (float*)(ws + 8 * MB);              // 4 MB
  u16* Rh = (u16*)(ws + 12 * MB);                // 2 MB
  u16* Rl = (u16*)(ws + 14 * MB);                // 2 MB
  u16* roth = (u16*)(ws + 16 * MB);              // 256 KB
  u16* rotl = (u16*)(ws + 16 * MB + 256 * 1024); // 256 KB
  float* colpart = (float*)(ws + 16 * MB + 512 * 1024);  // 128 KB
  float* trig = (float*)(ws + 16 * MB + 768 * 1024);     // 512 B
  u16* xn = (u16*)(ws + 17 * MB);                // 2 MB
  u16* gate_h = (u16*)(ws + 19 * MB);            // 2 MB
  u16* gate_l = (u16*)(ws + 21 * MB);            // 2 MB
  u16* Wp_h = (u16*)(ws + 23 * MB);              // 7 MB
  u16* Wp_l = (u16*)(ws + 30 * MB);              // 7 MB
  u16* Wb_h = (u16*)(ws + 37 * MB);              // 7 MB
  u16* Wb_l = (u16*)(ws + 44 * MB);              // 7 MB
  u16* lm_bf = (u16*)(ws + 51 * MB);             // 311 MB (optional)

  const size_t lm_elems = (size_t)NV * D;
  bool preconv = ws_size >= 51 * MB + lm_elems * 2;

  // weight preprocessing (every launch; deterministic)
  k_cvt2<<<512, 256, 0, stream>>>(gatew, gate_h, gate_l, (size_t)D * D / 4);
  k_cvt2<<<1024, 256, 0, stream>>>(Wp, Wp_h, Wp_l, (size_t)NCYC * 128 * D / 4);
  k_cvt2<<<1024, 256, 0, stream>>>(Wb, Wb_h, Wb_l, (size_t)NCYC * 128 * D / 4);
  if (preconv) k_cvt<<<2048, 256, 0, stream>>>(lmw, lm_bf, lm_elems / 4);

  k_gather<<<S, 256, 0, stream>>>(tokens, embed, x, xh, xl);

  for (int i = 0; i < NCYC; ++i) {
    k_colpart<<<32, 256, 0, stream>>>(x, colpart);
    if ((i & 3) == 0) {
      k_causal<<<dim3(S / CSR, D / CDC), 256, 0, stream>>>(x, Rh, Rl, decay);
      k_gemm_s<true, true><<<dim3(8, 8), 256, 0, stream>>>(Rh, Rl, gate_h, gate_l,
                                                           x, xh, xl, D, D);
    }
    k_angles<<<64, 64, 0, stream>>>(colpart, agw, bang + i * 64, trig);
    k_proj_rot<<<16, 256, 0, stream>>>(xh, xl, Wp_h + (size_t)i * 128 * D,
                                       Wp_l + (size_t)i * 128 * D, trig, roth, rotl);
    k_gemm_s<false, false><<<dim3(8, 8), 256, 0, stream>>>(roth, rotl,
                                                           Wb_h + (size_t)i * 128 * D,
                                                           Wb_l + (size_t)i * 128 * D,
                                                           R, nullptr, nullptr, D, 128);
    k_epilogue<<<S, 256, 0, stream>>>(x, xh, xl, R, scales + i * D, shifts + i * D,
                                      normw + i * D);
  }

  k_outnorm<<<S, 256, 0, stream>>>(x, onorm, xn);
  if (preconv)
    k_lm<true><<<9496, 256, 0, stream>>>(xn, lm_bf, out);
  else
    k_lm<false><<<9496, 256, 0, stream>>>(xn, lmw, out);
}

// Round 5
// 3085.384 us; speedup vs baseline: 1.3505x; 1.1898x over previous
//
#include <hip/hip_runtime.h>

typedef __attribute__((ext_vector_type(4))) float f32x4;
typedef __attribute__((ext_vector_type(8))) short bf16x8;
typedef unsigned short u16;
typedef unsigned int u32;
typedef __attribute__((ext_vector_type(4))) unsigned short u16x4;

#define EPS 1.1920929e-07f
#define S 1024
#define D 1024
#define NV 151936
#define NCYC 28

__device__ __forceinline__ u16 f2bf(float f) {  // RNE
  u32 u = __float_as_uint(f);
  return (u16)((u + 0x7fffu + ((u >> 16) & 1u)) >> 16);
}
__device__ __forceinline__ float bf2f(u16 h) {
  return __uint_as_float((u32)h << 16);
}
struct bfpair { u16 h, l; };
__device__ __forceinline__ bfpair split_bf(float v) {
  bfpair r;
  r.h = f2bf(v);
  r.l = f2bf(v - bf2f(r.h));
  return r;
}

__device__ __forceinline__ void gl16(const void* g, void* s) {
  __builtin_amdgcn_global_load_lds((const __attribute__((address_space(1))) u32*)g,
                                   (__attribute__((address_space(3))) u32*)s, 16, 0, 0);
}

// T2 swizzle: physical in-row 16B slot = logical slot ^ (row&7). c in u16 elems.
__device__ __forceinline__ int swz(int r, int c) { return c ^ ((r & 7) << 3); }

__device__ __forceinline__ float block_sum256(float v, float* sbuf) {
  #pragma unroll
  for (int off = 32; off; off >>= 1) v += __shfl_down(v, off);
  int lane = threadIdx.x & 63, w = threadIdx.x >> 6;
  if (lane == 0) sbuf[w] = v;
  __syncthreads();
  return sbuf[0] + sbuf[1] + sbuf[2] + sbuf[3];
}

// ---------------- f32 -> bf16 (RNE) ----------------
__global__ void k_cvt(const float* __restrict__ src, u16* __restrict__ dst, size_t n4) {
  size_t i = (size_t)blockIdx.x * 256 + threadIdx.x;
  size_t stride = (size_t)gridDim.x * 256;
  for (; i < n4; i += stride) {
    f32x4 v = ((const f32x4*)src)[i];
    u16x4 o;
    #pragma unroll
    for (int e = 0; e < 4; ++e) o[e] = f2bf(v[e]);
    ((u16x4*)dst)[i] = o;
  }
}

// ---------------- f32 -> (hi, lo) bf16 split ----------------
__global__ void k_cvt2(const float* __restrict__ src, u16* __restrict__ dh,
                       u16* __restrict__ dl, size_t n4) {
  size_t i = (size_t)blockIdx.x * 256 + threadIdx.x;
  size_t stride = (size_t)gridDim.x * 256;
  for (; i < n4; i += stride) {
    f32x4 v = ((const f32x4*)src)[i];
    u16x4 oh, ol;
    #pragma unroll
    for (int e = 0; e < 4; ++e) { bfpair p = split_bf(v[e]); oh[e] = p.h; ol[e] = p.l; }
    ((u16x4*)dh)[i] = oh;
    ((u16x4*)dl)[i] = ol;
  }
}

// ---------------- embedding gather (f32 + split mirror) ----------------
__global__ void k_gather(const int* __restrict__ tokens, const float* __restrict__ table,
                         float* __restrict__ x, u16* __restrict__ xh, u16* __restrict__ xl) {
  int s = blockIdx.x, t = threadIdx.x;
  int tok = tokens[s];
  f32x4 v = ((const f32x4*)(table + (size_t)tok * D))[t];
  ((f32x4*)(x + (size_t)s * D))[t] = v;
  u16x4 oh, ol;
  #pragma unroll
  for (int e = 0; e < 4; ++e) { bfpair p = split_bf(v[e]); oh[e] = p.h; ol[e] = p.l; }
  ((u16x4*)(xh + (size_t)s * D))[t] = oh;
  ((u16x4*)(xl + (size_t)s * D))[t] = ol;
}

// ---------------- column partial sums ----------------
__global__ void k_colpart(const float* __restrict__ x, float* __restrict__ cp) {
  int b = blockIdx.x, t = threadIdx.x;
  f32x4 acc = 0.f;
  for (int r = 0; r < 32; ++r)
    acc += *(const f32x4*)(x + (size_t)(b * 32 + r) * D + t * 4);
  *(f32x4*)(cp + b * D + t * 4) = acc;
}

// ---------------- causal EMA via windowed conv (dec^95 ~ 8e-15) -> split -----------
#define TAPS 96
#define CSR 64
#define CDC 64
__global__ __launch_bounds__(256) void k_causal(const float* __restrict__ x,
                                                u16* __restrict__ Rh, u16* __restrict__ Rl,
                                                const float* __restrict__ decay_p) {
  __shared__ float tile[CSR + TAPS - 1][CDC];
  int s0 = blockIdx.x * CSR, d0 = blockIdx.y * CDC;
  float dec = 1.f / (1.f + expf(-decay_p[0]));
  for (int idx = threadIdx.x; idx < (CSR + TAPS - 1) * CDC; idx += 256) {
    int r = idx / CDC, c = idx % CDC;
    int gs = s0 - (TAPS - 1) + r;
    tile[r][c] = (gs >= 0) ? x[(size_t)gs * D + d0 + c] : 0.f;
  }
  __syncthreads();
  int c = threadIdx.x % CDC, r0 = threadIdx.x / CDC;
  for (int rr = r0; rr < CSR; rr += 4) {
    float acc = 0.f, w = 1.f - dec;
    int base = rr + TAPS - 1;
    #pragma unroll 8
    for (int j = 0; j < TAPS; ++j) { acc += w * tile[base - j][c]; w *= dec; }
    bfpair p = split_bf(acc);
    Rh[(size_t)(s0 + rr) * D + d0 + c] = p.h;
    Rl[(size_t)(s0 + rr) * D + d0 + c] = p.l;
  }
}

// ------- split-bf16 MFMA GEMM (~f32 accurate), dbuf+swizzle ------------------------
// acc = Ah*Bh + Ah*Bl + Al*Bh
template <bool ADD, bool XBOUT>
__global__ __launch_bounds__(256) void k_gemm_s(const u16* __restrict__ Ah_,
                                                const u16* __restrict__ Al_,
                                                const u16* __restrict__ Bh_,
                                                const u16* __restrict__ Bl_,
                                                float* __restrict__ C,
                                                u16* __restrict__ Ch, u16* __restrict__ Cl,
                                                int N, int K) {
  __shared__ u16 Ash[2][128 * 64], Asl[2][128 * 64], Bsh[2][128 * 64], Bsl[2][128 * 64];
  const int m0 = blockIdx.x * 128, n0 = blockIdx.y * 128;
  const int t = threadIdx.x;
  const int wave = t >> 6, lane = t & 63;
  const int wm = (wave >> 1) * 64, wn = (wave & 1) * 64;
  const int fr = lane & 15, kb = lane >> 4;
  const int sr = t >> 3, skc = (t & 7) << 3;
  const int sswz = skc ^ ((sr & 7) << 3);  // source swizzle (r&7 == sr&7 for r=it*32+sr)
  f32x4 acc[4][4];
  #pragma unroll
  for (int i = 0; i < 4; ++i)
    #pragma unroll
    for (int j = 0; j < 4; ++j) acc[i][j] = 0.f;

  auto stage = [&](int buf, int k0) {
    #pragma unroll
    for (int it = 0; it < 4; ++it) {
      int r = it * 32 + sr;
      size_t ga = (size_t)(m0 + r) * K + k0 + sswz;
      size_t gb = (size_t)(n0 + r) * K + k0 + sswz;
      int so = r * 64 + skc;
      gl16(Ah_ + ga, &Ash[buf][so]);
      gl16(Al_ + ga, &Asl[buf][so]);
      gl16(Bh_ + gb, &Bsh[buf][so]);
      gl16(Bl_ + gb, &Bsl[buf][so]);
    }
  };

  const int nt = K >> 6;
  stage(0, 0);
  __syncthreads();
  for (int kt = 0; kt < nt; ++kt) {
    if (kt + 1 < nt) stage((kt + 1) & 1, (kt + 1) << 6);
    const int cur = kt & 1;
    #pragma unroll
    for (int ks = 0; ks < 2; ++ks) {
      const int cphys = (ks * 32 + kb * 8) ^ ((fr & 7) << 3);
      bf16x8 ah[4], al[4], bh[4], bl[4];
      #pragma unroll
      for (int i = 0; i < 4; ++i) {
        int o = (wm + i * 16 + fr) * 64 + cphys;
        ah[i] = *(const bf16x8*)&Ash[cur][o];
        al[i] = *(const bf16x8*)&Asl[cur][o];
      }
      #pragma unroll
      for (int j = 0; j < 4; ++j) {
        int o = (wn + j * 16 + fr) * 64 + cphys;
        bh[j] = *(const bf16x8*)&Bsh[cur][o];
        bl[j] = *(const bf16x8*)&Bsl[cur][o];
      }
      #pragma unroll
      for (int i = 0; i < 4; ++i)
        #pragma unroll
        for (int j = 0; j < 4; ++j) {
          acc[i][j] = __builtin_amdgcn_mfma_f32_16x16x32_bf16(ah[i], bh[j], acc[i][j], 0, 0, 0);
          acc[i][j] = __builtin_amdgcn_mfma_f32_16x16x32_bf16(ah[i], bl[j], acc[i][j], 0, 0, 0);
          acc[i][j] = __builtin_amdgcn_mfma_f32_16x16x32_bf16(al[i], bh[j], acc[i][j], 0, 0, 0);
        }
    }
    __syncthreads();
  }
  #pragma unroll
  for (int i = 0; i < 4; ++i)
    #pragma unroll
    for (int j = 0; j < 4; ++j)
      #pragma unroll
      for (int rg = 0; rg < 4; ++rg) {
        int m = m0 + wm + i * 16 + kb * 4 + rg;
        int n = n0 + wn + j * 16 + fr;
        float v = acc[i][j][rg];
        if (ADD) v += C[(size_t)m * N + n];
        C[(size_t)m * N + n] = v;
        if (XBOUT) {
          bfpair p = split_bf(v);
          Ch[(size_t)m * N + n] = p.h;
          Cl[(size_t)m * N + n] = p.l;
        }
      }
}

// ------- proj GEMM (split, dbuf, swizzle) + fused angles + rotation ----------------
__global__ __launch_bounds__(256) void k_proj_rot(const u16* __restrict__ xh,
                                                  const u16* __restrict__ xl,
                                                  const u16* __restrict__ Bh_,
                                                  const u16* __restrict__ Bl_,
                                                  const float* __restrict__ cp,
                                                  const float* __restrict__ agw,
                                                  const float* __restrict__ bang,
                                                  u16* __restrict__ roth,
                                                  u16* __restrict__ rotl) {
  __shared__ u16 Ash[2][64 * 64], Asl[2][64 * 64], Bsh[2][128 * 64], Bsl[2][128 * 64];
  __shared__ float colsum[1024];
  __shared__ float trig_s[128];
  const int m0 = blockIdx.x * 64;
  const int t = threadIdx.x;
  const int wave = t >> 6, lane = t & 63;
  const int fr = lane & 15, kb = lane >> 4;
  const int sr = t >> 3, skc = (t & 7) << 3;
  const int sswz = skc ^ ((sr & 7) << 3);

  // ---- angles prologue (redundant per block; removes k_angles launch) ----
  {
    int d0 = t * 4;
    f32x4 av = 0.f;
    for (int b = 0; b < 32; ++b) av += *(const f32x4*)(cp + b * D + d0);
    *(f32x4*)&colsum[d0] = av;
  }
  __syncthreads();
  for (int pp = 0; pp < 16; ++pp) {
    int p = wave * 16 + pp;
    float sum = 0.f;
    #pragma unroll
    for (int q = 0; q < 16; ++q) {
      int d = lane + q * 64;
      sum += colsum[d] * agw[p * D + d];
    }
    #pragma unroll
    for (int off = 32; off; off >>= 1) sum += __shfl_down(sum, off);
    if (lane == 0) {
      float ang = bang[p] + 0.1f * (sum * (1.f / 1024.f));
      trig_s[p] = cosf(ang);
      trig_s[64 + p] = sinf(ang);
    }
  }

  f32x4 acc[8];
  #pragma unroll
  for (int j = 0; j < 8; ++j) acc[j] = 0.f;

  auto stage = [&](int buf, int k0) {
    #pragma unroll
    for (int it = 0; it < 2; ++it) {
      int r = it * 32 + sr;
      size_t ga = (size_t)(m0 + r) * D + k0 + sswz;
      gl16(xh + ga, &Ash[buf][r * 64 + skc]);
      gl16(xl + ga, &Asl[buf][r * 64 + skc]);
    }
    #pragma unroll
    for (int it = 0; it < 4; ++it) {
      int r = it * 32 + sr;
      size_t gb = (size_t)r * D + k0 + sswz;
      gl16(Bh_ + gb, &Bsh[buf][r * 64 + skc]);
      gl16(Bl_ + gb, &Bsl[buf][r * 64 + skc]);
    }
  };

  stage(0, 0);
  __syncthreads();
  for (int kt = 0; kt < 16; ++kt) {
    if (kt < 15) stage((kt + 1) & 1, (kt + 1) << 6);
    const int cur = kt & 1;
    #pragma unroll
    for (int ks = 0; ks < 2; ++ks) {
      const int cphys = (ks * 32 + kb * 8) ^ ((fr & 7) << 3);
      int oa = (wave * 16 + fr) * 64 + cphys;
      bf16x8 ah = *(const bf16x8*)&Ash[cur][oa];
      bf16x8 al = *(const bf16x8*)&Asl[cur][oa];
      #pragma unroll
      for (int j = 0; j < 8; ++j) {
        int ob = (j * 16 + fr) * 64 + cphys;
        bf16x8 bh = *(const bf16x8*)&Bsh[cur][ob];
        bf16x8 bl = *(const bf16x8*)&Bsl[cur][ob];
        acc[j] = __builtin_amdgcn_mfma_f32_16x16x32_bf16(ah, bh, acc[j], 0, 0, 0);
        acc[j] = __builtin_amdgcn_mfma_f32_16x16x32_bf16(ah, bl, acc[j], 0, 0, 0);
        acc[j] = __builtin_amdgcn_mfma_f32_16x16x32_bf16(al, bh, acc[j], 0, 0, 0);
      }
    }
    __syncthreads();
  }
  #pragma unroll
  for (int j = 0; j < 4; ++j) {
    int p = j * 16 + fr;
    float ca = trig_s[p], sa = trig_s[64 + p];
    #pragma unroll
    for (int rg = 0; rg < 4; ++rg) {
      int m = m0 + wave * 16 + kb * 4 + rg;
      float va = acc[j][rg], vb = acc[j + 4][rg];
      bfpair pa = split_bf(va * ca - vb * sa);
      roth[m * 128 + p] = pa.h;
      rotl[m * 128 + p] = pa.l;
      bfpair pb = split_bf(va * sa + vb * ca);
      roth[m * 128 + 64 + p] = pb.h;
      rotl[m * 128 + 64 + p] = pb.l;
    }
  }
}

// ---------------- fused epilogue: x += rmsnorm(silu((x+R)*sc+sh) - x) * nw ---------
__global__ __launch_bounds__(256) void k_epilogue(float* __restrict__ x, u16* __restrict__ xh,
                                                  u16* __restrict__ xl,
                                                  const float* __restrict__ R,
                                                  const float* __restrict__ scale,
                                                  const float* __restrict__ shift,
                                                  const float* __restrict__ nw) {
  __shared__ float sbuf[4];
  int s = blockIdx.x, t = threadIdx.x;
  f32x4 xv = *(const f32x4*)(x + (size_t)s * D + t * 4);
  f32x4 rv = *(const f32x4*)(R + (size_t)s * D + t * 4);
  f32x4 sc = *(const f32x4*)(scale + t * 4);
  f32x4 sh = *(const f32x4*)(shift + t * 4);
  float y[4], ss = 0.f;
  #pragma unroll
  for (int c = 0; c < 4; ++c) {
    float xr = xv[c] + rv[c];
    float tt = xr * sc[c] + sh[c];
    float act = tt / (1.f + expf(-tt));
    y[c] = act - xv[c];
    ss += y[c] * y[c];
  }
  float total = block_sum256(ss, sbuf);
  float inv = rsqrtf(total * (1.f / (float)D) + EPS);
  f32x4 nwv = *(const f32x4*)(nw + t * 4);
  f32x4 o;
  u16x4 oh, ol;
  #pragma unroll
  for (int c = 0; c < 4; ++c) {
    o[c] = xv[c] + y[c] * inv * nwv[c];
    bfpair p = split_bf(o[c]);
    oh[c] = p.h;
    ol[c] = p.l;
  }
  *(f32x4*)(x + (size_t)s * D + t * 4) = o;
  *(u16x4*)(xh + (size_t)s * D + t * 4) = oh;
  *(u16x4*)(xl + (size_t)s * D + t * 4) = ol;
}

// ---------------- final rmsnorm -> bf16 ----------------
__global__ __launch_bounds__(256) void k_outnorm(const float* __restrict__ x,
                                                 const float* __restrict__ w,
                                                 u16* __restrict__ xn) {
  __shared__ float sbuf[4];
  int s = blockIdx.x, t = threadIdx.x;
  f32x4 xv = *(const f32x4*)(x + (size_t)s * D + t * 4);
  float total = block_sum256(xv[0]*xv[0] + xv[1]*xv[1] + xv[2]*xv[2] + xv[3]*xv[3], sbuf);
  float inv = rsqrtf(total * (1.f / (float)D) + EPS);
  f32x4 wv = *(const f32x4*)(w + t * 4);
  u16x4 o;
  #pragma unroll
  for (int c = 0; c < 4; ++c) o[c] = f2bf(xv[c] * inv * wv[c]);
  *(u16x4*)(xn + (size_t)s * D + t * 4) = o;
}

// ---------------- lm_head GEMM, m97-style + T2 swizzle, XCD-chunk swizzle ----------
// grid: 9496 = 8 m-tiles x 1187 n-tiles (1-D).
template <bool PRECONV>
__global__ __launch_bounds__(256) void k_lm(const u16* __restrict__ A,
                                            const void* __restrict__ Wsrc,
                                            float* __restrict__ out) {
  __shared__ u16 As[128 * 64];
  __shared__ u16 Bs[128 * 64];
  const int bid = blockIdx.x;
  const int lid = (bid & 7) * 1187 + (bid >> 3);  // bijective: 9496 = 8*1187
  const int m0 = (lid & 7) * 128;
  const int n0 = (lid >> 3) * 128;
  const int t = threadIdx.x;
  const int wave = t >> 6, lane = t & 63;
  const int wm = (wave >> 1) * 64, wn = (wave & 1) * 64;
  const int fr = lane & 15, kb = lane >> 4;
  const int sr = t >> 3, skc = (t & 7) << 3;
  const int sswz = skc ^ ((sr & 7) << 3);
  const u16* Wb16 = (const u16*)Wsrc;
  const float* Wf = (const float*)Wsrc;
  f32x4 acc[4][4];
  #pragma unroll
  for (int i = 0; i < 4; ++i)
    #pragma unroll
    for (int j = 0; j < 4; ++j) acc[i][j] = 0.f;

  for (int k0 = 0; k0 < D; k0 += 64) {
    #pragma unroll
    for (int it = 0; it < 4; ++it) {
      int r = it * 32 + sr;
      gl16(A + (size_t)(m0 + r) * D + k0 + sswz, As + r * 64 + skc);
    }
    if (PRECONV) {
      #pragma unroll
      for (int it = 0; it < 4; ++it) {
        int r = it * 32 + sr;
        gl16(Wb16 + (size_t)(n0 + r) * D + k0 + sswz, Bs + r * 64 + skc);
      }
    } else {
      #pragma unroll
      for (int it = 0; it < 4; ++it) {
        int r = it * 32 + sr;
        const float* src = Wf + (size_t)(n0 + r) * D + k0 + sswz;
        f32x4 v0 = *(const f32x4*)src;
        f32x4 v1 = *(const f32x4*)(src + 4);
        u16 h[8];
        #pragma unroll
        for (int e = 0; e < 4; ++e) { h[e] = f2bf(v0[e]); h[e + 4] = f2bf(v1[e]); }
        *(bf16x8*)&Bs[r * 64 + skc] = *(bf16x8*)h;
      }
    }
    __syncthreads();
    #pragma unroll
    for (int ks = 0; ks < 2; ++ks) {
      const int cphys = (ks * 32 + kb * 8) ^ ((fr & 7) << 3);
      bf16x8 a[4], b[4];
      #pragma unroll
      for (int i = 0; i < 4; ++i) a[i] = *(const bf16x8*)&As[(wm + i * 16 + fr) * 64 + cphys];
      #pragma unroll
      for (int j = 0; j < 4; ++j) b[j] = *(const bf16x8*)&Bs[(wn + j * 16 + fr) * 64 + cphys];
      #pragma unroll
      for (int i = 0; i < 4; ++i)
        #pragma unroll
        for (int j = 0; j < 4; ++j)
          acc[i][j] = __builtin_amdgcn_mfma_f32_16x16x32_bf16(a[i], b[j], acc[i][j], 0, 0, 0);
    }
    __syncthreads();
  }
  #pragma unroll
  for (int i = 0; i < 4; ++i)
    #pragma unroll
    for (int j = 0; j < 4; ++j)
      #pragma unroll
      for (int rg = 0; rg < 4; ++rg) {
        int m = m0 + wm + i * 16 + kb * 4 + rg;
        int n = n0 + wn + j * 16 + fr;
        out[(size_t)m * NV + n] = acc[i][j][rg];
      }
}

extern "C" void kernel_launch(void* const* d_in, const int* in_sizes, int n_in,
                              void* d_out, int out_size, void* d_ws, size_t ws_size,
                              hipStream_t stream) {
  const int* tokens = (const int*)d_in[0];
  const float* embed = (const float*)d_in[1];
  const float* Wp = (const float*)d_in[2];
  const float* Wb = (const float*)d_in[3];
  const float* bang = (const float*)d_in[4];
  const float* agw = (const float*)d_in[5];
  const float* scales = (const float*)d_in[6];
  const float* shifts = (const float*)d_in[7];
  const float* normw = (const float*)d_in[8];
  const float* decay = (const float*)d_in[9];
  const float* gatew = (const float*)d_in[10];
  const float* onorm = (const float*)d_in[11];
  const float* lmw = (const float*)d_in[12];
  float* out = (float*)d_out;

  char* ws = (char*)d_ws;
  const size_t MB = 1u << 20;
  float* x = (float*)ws;                         // 4 MB
  u16* xh = (u16*)(ws + 4 * MB);                 // 2 MB
  u16* xl = (u16*)(ws + 6 * MB);                 // 2 MB
  float* R = (float*)(ws + 8 * MB);              // 4 MB
  u16* Rh = (u16*)(ws + 12 * MB);                // 2 MB
  u16* Rl = (u16*)(ws + 14 * MB);                // 2 MB
  u16* roth = (u16*)(ws + 16 * MB);              // 256 KB
  u16* rotl = (u16*)(ws + 16 * MB + 256 * 1024); // 256 KB
  float* colpart = (float*)(ws + 16 * MB + 512 * 1024);  // 128 KB
  u16* xn = (u16*)(ws + 17 * MB);                // 2 MB
  u16* gate_h = (u16*)(ws + 19 * MB);            // 2 MB
  u16* gate_l = (u16*)(ws + 21 * MB);            // 2 MB
  u16* Wp_h = (u16*)(ws + 23 * MB);              // 7 MB
  u16* Wp_l = (u16*)(ws + 30 * MB);              // 7 MB
  u16* Wb_h = (u16*)(ws + 37 * MB);              // 7 MB
  u16* Wb_l = (u16*)(ws + 44 * MB);              // 7 MB
  u16* lm_bf = (u16*)(ws + 51 * MB);             // 311 MB (optional)

  const size_t lm_elems = (size_t)NV * D;
  bool preconv = ws_size >= 51 * MB + lm_elems * 2;

  // weight preprocessing (every launch; deterministic)
  k_cvt2<<<512, 256, 0, stream>>>(gatew, gate_h, gate_l, (size_t)D * D / 4);
  k_cvt2<<<1024, 256, 0, stream>>>(Wp, Wp_h, Wp_l, (size_t)NCYC * 128 * D / 4);
  k_cvt2<<<1024, 256, 0, stream>>>(Wb, Wb_h, Wb_l, (size_t)NCYC * 128 * D / 4);
  if (preconv) k_cvt<<<2048, 256, 0, stream>>>(lmw, lm_bf, lm_elems / 4);

  k_gather<<<S, 256, 0, stream>>>(tokens, embed, x, xh, xl);

  for (int i = 0; i < NCYC; ++i) {
    k_colpart<<<32, 256, 0, stream>>>(x, colpart);
    if ((i & 3) == 0) {
      k_causal<<<dim3(S / CSR, D / CDC), 256, 0, stream>>>(x, Rh, Rl, decay);
      k_gemm_s<true, true><<<dim3(8, 8), 256, 0, stream>>>(Rh, Rl, gate_h, gate_l,
                                                           x, xh, xl, D, D);
    }
    k_proj_rot<<<16, 256, 0, stream>>>(xh, xl, Wp_h + (size_t)i * 128 * D,
                                       Wp_l + (size_t)i * 128 * D, colpart, agw,
                                       bang + i * 64, roth, rotl);
    k_gemm_s<false, false><<<dim3(8, 8), 256, 0, stream>>>(roth, rotl,
                                                           Wb_h + (size_t)i * 128 * D,
                                                           Wb_l + (size_t)i * 128 * D,
                                                           R, nullptr, nullptr, D, 128);
    k_epilogue<<<S, 256, 0, stream>>>(x, xh, xl, R, scales + i * D, shifts + i * D,
                                      normw + i * D);
  }

  k_outnorm<<<S, 256, 0, stream>>>(x, onorm, xn);
  if (preconv)
    k_lm<true><<<9496, 256, 0, stream>>>(xn, lm_bf, out);
  else
    k_lm<false><<<9496, 256, 0, stream>>>(xn, lmw, out);
}